// Round 1
// baseline (130.345 us; speedup 1.0000x reference)
//
#include <hip/hip_runtime.h>

// ---------------------------------------------------------------------------
// KAN forward as one bf16 MFMA GEMM:
//   y[n,o] = sum_i ( silu(x[n,i])*scale_base[o,i]
//                  + sum_b basis_b(x[n,i]) * scale_sp[o,i]*coef[o,i,b] ) + bias[o]
// A[n, i*8+s], W[o, i*8+s]: s=0 -> (silu, scale_base); s=1..6 -> (basis, sp*coef);
// s=7 -> zero pad.  K = 512*8 = 4096.
// ---------------------------------------------------------------------------

typedef short  bf16x8 __attribute__((ext_vector_type(8)));
typedef float  f32x4  __attribute__((ext_vector_type(4)));

#define NROWS 16384
#define DIN   512
#define DOUT  512
#define BM    128
#define BN    256
#define NKT   64          // K-steps; each covers 8 input features (64 k-units)
#define WT_TILE_BYTES 32768   // 256 rows x 64 bf16 (128B rows)

__device__ __forceinline__ unsigned short f2bf(float f) {
    unsigned int u = __float_as_uint(f);
    u += 0x7fffu + ((u >> 16) & 1u);          // round-to-nearest-even
    return (unsigned short)(u >> 16);
}

// activation vector for one x value: [silu, basis0..5, 0] as 8 bf16
__device__ __forceinline__ bf16x8 kan_act(float xv) {
    float S = (xv + 3.0f) * 1.5f;             // knot-space coordinate, cells [m, m+1)
    float r[10];
#pragma unroll
    for (int m = 0; m < 10; ++m) {
        float t = fmaxf(S - (float)m, 0.0f);  // truncated power basis
        r[m] = t * t * t;
    }
    float sc = (S < 9.0f) ? (1.0f / 6.0f) : 0.0f;  // x>=3 -> all basis zero; S<0 -> r==0 anyway
    float e  = __expf(-xv);
    float si = xv / (1.0f + e);               // silu
    bf16x8 a;
    a[0] = (short)f2bf(si);
#pragma unroll
    for (int j = 0; j < 6; ++j) {
        float b = r[j] - 4.0f * r[j+1] + 6.0f * r[j+2] - 4.0f * r[j+3] + r[j+4];
        a[1 + j] = (short)f2bf(b * sc);
    }
    a[7] = 0;
    return a;
}

// ---------------------------------------------------------------------------
// Prep: pack W into ws as bf16, tiled per (ntile, kstep) in the exact LDS image
// (pre-XOR-swizzled) so GEMM can global_load_lds it linearly.
//   tile(nt,kt): 256 rows (o_local) x 128 bytes; element (ol, colbyte):
//   byte = ol*128 + (colbyte ^ ((ol&7)<<4))
// ---------------------------------------------------------------------------
__global__ __launch_bounds__(256) void kan_prep(
    const float* __restrict__ coef, const float* __restrict__ scale_base,
    const float* __restrict__ scale_sp, unsigned short* __restrict__ wt)
{
    int t = blockIdx.x * 256 + threadIdx.x;   // (o,i) pair, 0..262143
    int o = t >> 9;
    int i = t & 511;
    float sb = scale_base[t];
    float sp = scale_sp[t];
    const float* cp = coef + (size_t)t * 6;
    bf16x8 w;
    w[0] = (short)f2bf(sb);
#pragma unroll
    for (int b = 0; b < 6; ++b) w[1 + b] = (short)f2bf(sp * cp[b]);
    w[7] = 0;
    int nt = o >> 8;
    int ol = o & 255;
    int kt = i >> 3;
    int colbyte = (i & 7) << 4;               // 16 bytes per feature (8 bf16 slots)
    unsigned off = (unsigned)((nt * NKT + kt) * WT_TILE_BYTES
                              + ol * 128 + (colbyte ^ ((ol & 7) << 4)));
    *(bf16x8*)((char*)wt + off) = w;
}

__device__ __forceinline__ void gload_lds16(const void* g, void* l) {
    __builtin_amdgcn_global_load_lds(
        (const __attribute__((address_space(1))) void*)g,
        (__attribute__((address_space(3))) void*)l, 16, 0, 0);
}

// ---------------------------------------------------------------------------
// Fused GEMM: BM=128 x BN=256, BK=64 k-units (8 features), 512 threads (8 waves 2x4),
// mfma_f32_16x16x32_bf16, wave tile 64x64 (4x4 fragments).
// ---------------------------------------------------------------------------
__global__ __launch_bounds__(512, 2) void kan_gemm(
    const float* __restrict__ x, const unsigned short* __restrict__ wt,
    const float* __restrict__ bias, float* __restrict__ y)
{
    __shared__ char As[BM * 128];   // 16 KB, swizzled rows of 64 bf16
    __shared__ char Ws[BN * 128];   // 32 KB

    const int tid  = threadIdx.x;
    const int lane = tid & 63;
    const int wid  = tid >> 6;

    // bijective XCD-aware swizzle: 256 wgs, 8 XCDs -> each XCD a contiguous chunk
    int bid = blockIdx.x;
    int wg  = (bid & 7) * 32 + (bid >> 3);
    int mt  = wg & 127;
    int nt  = wg >> 7;

    const int row0 = mt * BM;
    const int col0 = nt * BN;

    const int wm = wid >> 2;        // 0..1
    const int wn = wid & 3;         // 0..3

    // A staging: thread -> (row ar, feature-pair ap); loads float2 of x
    const int ar = tid >> 2;        // 0..127
    const int ap = tid & 3;         // 0..3
    const float* xp = x + (size_t)(row0 + ar) * DIN + ap * 2;
    char* as_row = As + ar * 128;
    const int as_sw = (ar & 7) << 4;

    const char* wsrc = (const char*)wt + (size_t)nt * NKT * WT_TILE_BYTES;

    f32x4 acc[4][4];
#pragma unroll
    for (int m2 = 0; m2 < 4; ++m2)
#pragma unroll
        for (int n2 = 0; n2 < 4; ++n2) {
            f32x4 z = {0.f, 0.f, 0.f, 0.f};
            acc[m2][n2] = z;
        }

    const int fr = lane & 15;       // fragment row/col
    const int fg = lane >> 4;       // k-group 0..3

    for (int kt = 0; kt < NKT; ++kt) {
        __syncthreads();
        // ---- stage W: 32 KB, 4 issues x (512 lanes x 16B), linear (pre-swizzled in ws)
        {
            const char* s = wsrc + kt * WT_TILE_BYTES + wid * 1024 + lane * 16;
            char* d = Ws + wid * 1024;
#pragma unroll
            for (int q = 0; q < 4; ++q)
                gload_lds16(s + q * 8192, d + q * 8192);
        }
        // ---- stage A: load 2 x-values, compute activations, swizzled LDS write
        {
            float2 xv = *(const float2*)(xp + kt * 8);
            bf16x8 a0 = kan_act(xv.x);
            bf16x8 a1 = kan_act(xv.y);
            int c0 = (ap * 2) << 4;
            *(bf16x8*)(as_row + (c0 ^ as_sw))        = a0;
            *(bf16x8*)(as_row + ((c0 + 16) ^ as_sw)) = a1;
        }
        __syncthreads();
        // ---- MFMA over BK=64 (two k-slices of 32)
#pragma unroll
        for (int ks = 0; ks < 2; ++ks) {
            const int cb = ks * 64 + fg * 16;   // byte col within row
            bf16x8 af[4], bf[4];
#pragma unroll
            for (int m2 = 0; m2 < 4; ++m2) {
                int rr = wm * 64 + m2 * 16 + fr;
                af[m2] = *(const bf16x8*)(As + rr * 128 + (cb ^ ((rr & 7) << 4)));
            }
#pragma unroll
            for (int n2 = 0; n2 < 4; ++n2) {
                int wr = wn * 64 + n2 * 16 + fr;
                bf[n2] = *(const bf16x8*)(Ws + wr * 128 + (cb ^ ((wr & 7) << 4)));
            }
#pragma unroll
            for (int m2 = 0; m2 < 4; ++m2)
#pragma unroll
                for (int n2 = 0; n2 < 4; ++n2)
                    acc[m2][n2] = __builtin_amdgcn_mfma_f32_16x16x32_bf16(
                        af[m2], bf[n2], acc[m2][n2], 0, 0, 0);
        }
    }

    // ---- epilogue: C/D layout col = lane&15, row = (lane>>4)*4 + reg
    const int orow0 = row0 + wm * 64 + fg * 4;
    const int ocol0 = col0 + wn * 64 + fr;
#pragma unroll
    for (int n2 = 0; n2 < 4; ++n2) {
        float bv = bias[ocol0 + n2 * 16];
#pragma unroll
        for (int m2 = 0; m2 < 4; ++m2) {
#pragma unroll
            for (int r = 0; r < 4; ++r) {
                y[(size_t)(orow0 + m2 * 16 + r) * DOUT + (ocol0 + n2 * 16)]
                    = acc[m2][n2][r] + bv;
            }
        }
    }
}

extern "C" void kernel_launch(void* const* d_in, const int* in_sizes, int n_in,
                              void* d_out, int out_size, void* d_ws, size_t ws_size,
                              hipStream_t stream)
{
    const float* x          = (const float*)d_in[0];
    const float* coef       = (const float*)d_in[1];
    const float* scale_base = (const float*)d_in[2];
    const float* scale_sp   = (const float*)d_in[3];
    const float* bias       = (const float*)d_in[4];
    unsigned short* wt = (unsigned short*)d_ws;   // needs 4 MB (2 ntiles * 64 kt * 32 KB)
    float* y = (float*)d_out;

    kan_prep<<<1024, 256, 0, stream>>>(coef, scale_base, scale_sp, wt);
    kan_gemm<<<256, 512, 0, stream>>>(x, wt, bias, y);
}

// Round 2
// 105.120 us; speedup vs baseline: 1.2400x; 1.2400x over previous
//
#include <hip/hip_runtime.h>

// ---------------------------------------------------------------------------
// KAN forward as one bf16 MFMA GEMM:
//   y[n,o] = sum_i ( silu(x[n,i])*scale_base[o,i]
//                  + sum_b basis_b(x[n,i]) * scale_sp[o,i]*coef[o,i,b] ) + bias[o]
// A[n, i*8+s], W[o, i*8+s]: s=0 -> (silu, scale_base); s=1..6 -> (basis, sp*coef);
// s=7 -> zero pad.  K = 512*8 = 4096.
// Round 2: double-buffered LDS pipeline (1 barrier/iter, stage-next before
// compute-current), x reg-prefetch, setprio around MFMA.
// ---------------------------------------------------------------------------

typedef short  bf16x8 __attribute__((ext_vector_type(8)));
typedef float  f32x4  __attribute__((ext_vector_type(4)));

#define NROWS 16384
#define DIN   512
#define DOUT  512
#define BM    128
#define BN    256
#define NKT   64          // K-steps; each covers 8 input features (64 k-units)
#define WT_TILE_BYTES 32768   // 256 rows x 64 bf16 (128B rows)

__device__ __forceinline__ unsigned short f2bf(float f) {
    unsigned int u = __float_as_uint(f);
    u += 0x7fffu + ((u >> 16) & 1u);          // round-to-nearest-even
    return (unsigned short)(u >> 16);
}

// activation vector for one x value: [silu, basis0..5, 0] as 8 bf16
__device__ __forceinline__ bf16x8 kan_act(float xv) {
    float S = (xv + 3.0f) * 1.5f;             // knot-space coordinate, cells [m, m+1)
    float r[10];
#pragma unroll
    for (int m = 0; m < 10; ++m) {
        float t = fmaxf(S - (float)m, 0.0f);  // truncated power basis
        r[m] = t * t * t;
    }
    float sc = (S < 9.0f) ? (1.0f / 6.0f) : 0.0f;  // x>=3 -> all basis zero; S<0 -> r==0 anyway
    float e  = __expf(-xv);
    float si = xv / (1.0f + e);               // silu
    bf16x8 a;
    a[0] = (short)f2bf(si);
#pragma unroll
    for (int j = 0; j < 6; ++j) {
        float b = r[j] - 4.0f * r[j+1] + 6.0f * r[j+2] - 4.0f * r[j+3] + r[j+4];
        a[1 + j] = (short)f2bf(b * sc);
    }
    a[7] = 0;
    return a;
}

// ---------------------------------------------------------------------------
// Prep: pack W into ws as bf16, tiled per (ntile, kstep) in the exact LDS image
// (pre-XOR-swizzled) so GEMM can global_load_lds it linearly.
//   tile(nt,kt): 256 rows (o_local) x 128 bytes; element (ol, colbyte):
//   byte = ol*128 + (colbyte ^ ((ol&7)<<4))
// ---------------------------------------------------------------------------
__global__ __launch_bounds__(256) void kan_prep(
    const float* __restrict__ coef, const float* __restrict__ scale_base,
    const float* __restrict__ scale_sp, unsigned short* __restrict__ wt)
{
    int t = blockIdx.x * 256 + threadIdx.x;   // (o,i) pair, 0..262143
    int o = t >> 9;
    int i = t & 511;
    float sb = scale_base[t];
    float sp = scale_sp[t];
    const float* cp = coef + (size_t)t * 6;
    bf16x8 w;
    w[0] = (short)f2bf(sb);
#pragma unroll
    for (int b = 0; b < 6; ++b) w[1 + b] = (short)f2bf(sp * cp[b]);
    w[7] = 0;
    int nt = o >> 8;
    int ol = o & 255;
    int kt = i >> 3;
    int colbyte = (i & 7) << 4;               // 16 bytes per feature (8 bf16 slots)
    unsigned off = (unsigned)((nt * NKT + kt) * WT_TILE_BYTES
                              + ol * 128 + (colbyte ^ ((ol & 7) << 4)));
    *(bf16x8*)((char*)wt + off) = w;
}

__device__ __forceinline__ void gload_lds16(const void* g, void* l) {
    __builtin_amdgcn_global_load_lds(
        (const __attribute__((address_space(1))) void*)g,
        (__attribute__((address_space(3))) void*)l, 16, 0, 0);
}

// ---------------------------------------------------------------------------
// Fused GEMM: BM=128 x BN=256, BK=64 k-units (8 features), 512 threads (8 waves 2x4),
// mfma_f32_16x16x32_bf16, wave tile 64x64 (4x4 fragments).
// Double-buffered LDS; per iter: stage(next) || compute(cur); 1 barrier.
// ---------------------------------------------------------------------------
__global__ __launch_bounds__(512, 2) void kan_gemm(
    const float* __restrict__ x, const unsigned short* __restrict__ wt,
    const float* __restrict__ bias, float* __restrict__ y)
{
    __shared__ char As[2][BM * 128];   // 2 x 16 KB, swizzled rows of 64 bf16
    __shared__ char Ws[2][BN * 128];   // 2 x 32 KB

    const int tid  = threadIdx.x;
    const int lane = tid & 63;
    const int wid  = tid >> 6;

    // bijective XCD-aware swizzle: 256 wgs, 8 XCDs -> each XCD a contiguous chunk
    int bid = blockIdx.x;
    int wg  = (bid & 7) * 32 + (bid >> 3);
    int mt  = wg & 127;
    int nt  = wg >> 7;

    const int row0 = mt * BM;
    const int col0 = nt * BN;

    const int wm = wid >> 2;        // 0..1
    const int wn = wid & 3;         // 0..3

    // A staging: thread -> (row ar, feature-pair ap); loads float2 of x
    const int ar = tid >> 2;        // 0..127
    const int ap = tid & 3;         // 0..3
    const float* xp = x + (size_t)(row0 + ar) * DIN + ap * 2;
    const int as_sw = (ar & 7) << 4;
    const int c0 = (ap * 2) << 4;

    const char* wsrc = (const char*)wt + (size_t)nt * NKT * WT_TILE_BYTES;

    f32x4 acc[4][4];
#pragma unroll
    for (int m2 = 0; m2 < 4; ++m2)
#pragma unroll
        for (int n2 = 0; n2 < 4; ++n2) {
            f32x4 z = {0.f, 0.f, 0.f, 0.f};
            acc[m2][n2] = z;
        }

    const int fr = lane & 15;       // fragment row/col
    const int fg = lane >> 4;       // k-group 0..3

    // ---------------- prologue: stage buffer 0 for kt=0 ----------------
    {
        const char* s = wsrc + 0 * WT_TILE_BYTES + wid * 1024 + lane * 16;
        char* d = &Ws[0][wid * 1024];
#pragma unroll
        for (int q = 0; q < 4; ++q)
            gload_lds16(s + q * 8192, d + q * 8192);
        float2 xa = *(const float2*)(xp);
        bf16x8 a0 = kan_act(xa.x);
        bf16x8 a1 = kan_act(xa.y);
        char* rowp = &As[0][ar * 128];
        *(bf16x8*)(rowp + (c0 ^ as_sw))        = a0;
        *(bf16x8*)(rowp + ((c0 + 16) ^ as_sw)) = a1;
    }
    float2 xb = *(const float2*)(xp + 8);   // x for kt=1
    asm volatile("s_waitcnt vmcnt(0) lgkmcnt(0)" ::: "memory");
    __builtin_amdgcn_s_barrier();

    // ---------------- main loop ----------------
    int cur = 0;
    for (int kt = 0; kt < NKT; ++kt) {
        const int nxt = cur ^ 1;
        const bool has_next = (kt + 1 < NKT);

        if (has_next) {
            // issue next W tile loads (HBM/L2 latency hides under MFMA below)
            const char* s = wsrc + (kt + 1) * WT_TILE_BYTES + wid * 1024 + lane * 16;
            char* d = &Ws[nxt][wid * 1024];
#pragma unroll
            for (int q = 0; q < 4; ++q)
                gload_lds16(s + q * 8192, d + q * 8192);
            // compute next A activations (VALU overlaps other waves' MFMA)
            bf16x8 a0 = kan_act(xb.x);
            bf16x8 a1 = kan_act(xb.y);
            char* rowp = &As[nxt][ar * 128];
            *(bf16x8*)(rowp + (c0 ^ as_sw))        = a0;
            *(bf16x8*)(rowp + ((c0 + 16) ^ as_sw)) = a1;
            if (kt + 2 < NKT)
                xb = *(const float2*)(xp + (kt + 2) * 8);
        }

        // ---- compute on buf[cur]: BK=64 as two k-slices of 32
#pragma unroll
        for (int ks = 0; ks < 2; ++ks) {
            const int cb = ks * 64 + fg * 16;   // byte col within row
            bf16x8 af[4], bf[4];
#pragma unroll
            for (int m2 = 0; m2 < 4; ++m2) {
                int rr = wm * 64 + m2 * 16 + fr;
                af[m2] = *(const bf16x8*)(&As[cur][0] + rr * 128 + (cb ^ ((rr & 7) << 4)));
            }
#pragma unroll
            for (int n2 = 0; n2 < 4; ++n2) {
                int wr = wn * 64 + n2 * 16 + fr;
                bf[n2] = *(const bf16x8*)(&Ws[cur][0] + wr * 128 + (cb ^ ((wr & 7) << 4)));
            }
            __builtin_amdgcn_s_setprio(1);
#pragma unroll
            for (int m2 = 0; m2 < 4; ++m2)
#pragma unroll
                for (int n2 = 0; n2 < 4; ++n2)
                    acc[m2][n2] = __builtin_amdgcn_mfma_f32_16x16x32_bf16(
                        af[m2], bf[n2], acc[m2][n2], 0, 0, 0);
            __builtin_amdgcn_s_setprio(0);
        }

        if (has_next) {
            asm volatile("s_waitcnt vmcnt(0) lgkmcnt(0)" ::: "memory");
            __builtin_amdgcn_s_barrier();
        }
        cur = nxt;
    }

    // ---- epilogue: C/D layout col = lane&15, row = (lane>>4)*4 + reg
    const int orow0 = row0 + wm * 64 + fg * 4;
    const int ocol0 = col0 + wn * 64 + fr;
#pragma unroll
    for (int n2 = 0; n2 < 4; ++n2) {
        float bv = bias[ocol0 + n2 * 16];
#pragma unroll
        for (int m2 = 0; m2 < 4; ++m2) {
#pragma unroll
            for (int r = 0; r < 4; ++r) {
                y[(size_t)(orow0 + m2 * 16 + r) * DOUT + (ocol0 + n2 * 16)]
                    = acc[m2][n2][r] + bv;
            }
        }
    }
}

extern "C" void kernel_launch(void* const* d_in, const int* in_sizes, int n_in,
                              void* d_out, int out_size, void* d_ws, size_t ws_size,
                              hipStream_t stream)
{
    const float* x          = (const float*)d_in[0];
    const float* coef       = (const float*)d_in[1];
    const float* scale_base = (const float*)d_in[2];
    const float* scale_sp   = (const float*)d_in[3];
    const float* bias       = (const float*)d_in[4];
    unsigned short* wt = (unsigned short*)d_ws;   // needs 4 MB (2 ntiles * 64 kt * 32 KB)
    float* y = (float*)d_out;

    kan_prep<<<1024, 256, 0, stream>>>(coef, scale_base, scale_sp, wt);
    kan_gemm<<<256, 512, 0, stream>>>(x, wt, bias, y);
}

// Round 3
// 104.847 us; speedup vs baseline: 1.2432x; 1.0026x over previous
//
#include <hip/hip_runtime.h>

// ---------------------------------------------------------------------------
// KAN forward as one bf16 MFMA GEMM:
//   y[n,o] = sum_i ( silu(x[n,i])*scale_base[o,i]
//                  + sum_b basis_b(x[n,i]) * scale_sp[o,i]*coef[o,i,b] ) + bias[o]
// A[n, i*8+s], W[o, i*8+s]: s=0 -> (silu, scale_base); s=1..6 -> (basis, sp*coef);
// s=7 -> zero pad.  K = 512*8 = 4096.
// Round 2: double-buffered LDS pipeline (1 barrier/iter, stage-next before
// compute-current), x reg-prefetch, setprio around MFMA.
// ---------------------------------------------------------------------------

typedef short  bf16x8 __attribute__((ext_vector_type(8)));
typedef float  f32x4  __attribute__((ext_vector_type(4)));

#define NROWS 16384
#define DIN   512
#define DOUT  512
#define BM    128
#define BN    256
#define NKT   64          // K-steps; each covers 8 input features (64 k-units)
#define WT_TILE_BYTES 32768   // 256 rows x 64 bf16 (128B rows)

__device__ __forceinline__ unsigned short f2bf(float f) {
    unsigned int u = __float_as_uint(f);
    u += 0x7fffu + ((u >> 16) & 1u);          // round-to-nearest-even
    return (unsigned short)(u >> 16);
}

// activation vector for one x value: [silu, basis0..5, 0] as 8 bf16
__device__ __forceinline__ bf16x8 kan_act(float xv) {
    float S = (xv + 3.0f) * 1.5f;             // knot-space coordinate, cells [m, m+1)
    float r[10];
#pragma unroll
    for (int m = 0; m < 10; ++m) {
        float t = fmaxf(S - (float)m, 0.0f);  // truncated power basis
        r[m] = t * t * t;
    }
    float sc = (S < 9.0f) ? (1.0f / 6.0f) : 0.0f;  // x>=3 -> all basis zero; S<0 -> r==0 anyway
    float e  = __expf(-xv);
    float si = xv / (1.0f + e);               // silu
    bf16x8 a;
    a[0] = (short)f2bf(si);
#pragma unroll
    for (int j = 0; j < 6; ++j) {
        float b = r[j] - 4.0f * r[j+1] + 6.0f * r[j+2] - 4.0f * r[j+3] + r[j+4];
        a[1 + j] = (short)f2bf(b * sc);
    }
    a[7] = 0;
    return a;
}

// ---------------------------------------------------------------------------
// Prep: pack W into ws as bf16, tiled per (ntile, kstep) in the exact LDS image
// (pre-XOR-swizzled) so GEMM can global_load_lds it linearly.
//   tile(nt,kt): 256 rows (o_local) x 128 bytes; element (ol, colbyte):
//   byte = ol*128 + (colbyte ^ ((ol&7)<<4))
// ---------------------------------------------------------------------------
__global__ __launch_bounds__(256) void kan_prep(
    const float* __restrict__ coef, const float* __restrict__ scale_base,
    const float* __restrict__ scale_sp, unsigned short* __restrict__ wt)
{
    int t = blockIdx.x * 256 + threadIdx.x;   // (o,i) pair, 0..262143
    int o = t >> 9;
    int i = t & 511;
    float sb = scale_base[t];
    float sp = scale_sp[t];
    const float* cp = coef + (size_t)t * 6;
    bf16x8 w;
    w[0] = (short)f2bf(sb);
#pragma unroll
    for (int b = 0; b < 6; ++b) w[1 + b] = (short)f2bf(sp * cp[b]);
    w[7] = 0;
    int nt = o >> 8;
    int ol = o & 255;
    int kt = i >> 3;
    int colbyte = (i & 7) << 4;               // 16 bytes per feature (8 bf16 slots)
    unsigned off = (unsigned)((nt * NKT + kt) * WT_TILE_BYTES
                              + ol * 128 + (colbyte ^ ((ol & 7) << 4)));
    *(bf16x8*)((char*)wt + off) = w;
}

__device__ __forceinline__ void gload_lds16(const void* g, void* l) {
    __builtin_amdgcn_global_load_lds(
        (const __attribute__((address_space(1))) void*)g,
        (__attribute__((address_space(3))) void*)l, 16, 0, 0);
}

// ---------------------------------------------------------------------------
// Fused GEMM: BM=128 x BN=256, BK=64 k-units (8 features), 512 threads (8 waves 2x4),
// mfma_f32_16x16x32_bf16, wave tile 64x64 (4x4 fragments).
// Double-buffered LDS; per iter: stage(next) || compute(cur); 1 barrier.
// ---------------------------------------------------------------------------
__global__ __launch_bounds__(512, 2) void kan_gemm(
    const float* __restrict__ x, const unsigned short* __restrict__ wt,
    const float* __restrict__ bias, float* __restrict__ y)
{
    __shared__ char As[2][BM * 128];   // 2 x 16 KB, swizzled rows of 64 bf16
    __shared__ char Ws[2][BN * 128];   // 2 x 32 KB

    const int tid  = threadIdx.x;
    const int lane = tid & 63;
    const int wid  = tid >> 6;

    // bijective XCD-aware swizzle: 256 wgs, 8 XCDs -> each XCD a contiguous chunk
    int bid = blockIdx.x;
    int wg  = (bid & 7) * 32 + (bid >> 3);
    int mt  = wg & 127;
    int nt  = wg >> 7;

    const int row0 = mt * BM;
    const int col0 = nt * BN;

    const int wm = wid >> 2;        // 0..1
    const int wn = wid & 3;         // 0..3

    // A staging: thread -> (row ar, feature-pair ap); loads float2 of x
    const int ar = tid >> 2;        // 0..127
    const int ap = tid & 3;         // 0..3
    const float* xp = x + (size_t)(row0 + ar) * DIN + ap * 2;
    const int as_sw = (ar & 7) << 4;
    const int c0 = (ap * 2) << 4;

    const char* wsrc = (const char*)wt + (size_t)nt * NKT * WT_TILE_BYTES;

    f32x4 acc[4][4];
#pragma unroll
    for (int m2 = 0; m2 < 4; ++m2)
#pragma unroll
        for (int n2 = 0; n2 < 4; ++n2) {
            f32x4 z = {0.f, 0.f, 0.f, 0.f};
            acc[m2][n2] = z;
        }

    const int fr = lane & 15;       // fragment row/col
    const int fg = lane >> 4;       // k-group 0..3

    // ---------------- prologue: stage buffer 0 for kt=0 ----------------
    {
        const char* s = wsrc + 0 * WT_TILE_BYTES + wid * 1024 + lane * 16;
        char* d = &Ws[0][wid * 1024];
#pragma unroll
        for (int q = 0; q < 4; ++q)
            gload_lds16(s + q * 8192, d + q * 8192);
        float2 xa = *(const float2*)(xp);
        bf16x8 a0 = kan_act(xa.x);
        bf16x8 a1 = kan_act(xa.y);
        char* rowp = &As[0][ar * 128];
        *(bf16x8*)(rowp + (c0 ^ as_sw))        = a0;
        *(bf16x8*)(rowp + ((c0 + 16) ^ as_sw)) = a1;
    }
    float2 xb = *(const float2*)(xp + 8);   // x for kt=1
    asm volatile("s_waitcnt vmcnt(0) lgkmcnt(0)" ::: "memory");
    __builtin_amdgcn_s_barrier();

    // ---------------- main loop ----------------
    int cur = 0;
    for (int kt = 0; kt < NKT; ++kt) {
        const int nxt = cur ^ 1;
        const bool has_next = (kt + 1 < NKT);

        if (has_next) {
            // issue next W tile loads (HBM/L2 latency hides under MFMA below)
            const char* s = wsrc + (kt + 1) * WT_TILE_BYTES + wid * 1024 + lane * 16;
            char* d = &Ws[nxt][wid * 1024];
#pragma unroll
            for (int q = 0; q < 4; ++q)
                gload_lds16(s + q * 8192, d + q * 8192);
            // compute next A activations (VALU overlaps other waves' MFMA)
            bf16x8 a0 = kan_act(xb.x);
            bf16x8 a1 = kan_act(xb.y);
            char* rowp = &As[nxt][ar * 128];
            *(bf16x8*)(rowp + (c0 ^ as_sw))        = a0;
            *(bf16x8*)(rowp + ((c0 + 16) ^ as_sw)) = a1;
            if (kt + 2 < NKT)
                xb = *(const float2*)(xp + (kt + 2) * 8);
        }

        // ---- compute on buf[cur]: BK=64 as two k-slices of 32
#pragma unroll
        for (int ks = 0; ks < 2; ++ks) {
            const int cb = ks * 64 + fg * 16;   // byte col within row
            bf16x8 af[4], bf[4];
#pragma unroll
            for (int m2 = 0; m2 < 4; ++m2) {
                int rr = wm * 64 + m2 * 16 + fr;
                af[m2] = *(const bf16x8*)(&As[cur][0] + rr * 128 + (cb ^ ((rr & 7) << 4)));
            }
#pragma unroll
            for (int n2 = 0; n2 < 4; ++n2) {
                int wr = wn * 64 + n2 * 16 + fr;
                bf[n2] = *(const bf16x8*)(&Ws[cur][0] + wr * 128 + (cb ^ ((wr & 7) << 4)));
            }
            __builtin_amdgcn_s_setprio(1);
#pragma unroll
            for (int m2 = 0; m2 < 4; ++m2)
#pragma unroll
                for (int n2 = 0; n2 < 4; ++n2)
                    acc[m2][n2] = __builtin_amdgcn_mfma_f32_16x16x32_bf16(
                        af[m2], bf[n2], acc[m2][n2], 0, 0, 0);
            __builtin_amdgcn_s_setprio(0);
        }

        if (has_next) {
            asm volatile("s_waitcnt vmcnt(0) lgkmcnt(0)" ::: "memory");
            __builtin_amdgcn_s_barrier();
        }
        cur = nxt;
    }

    // ---- epilogue: C/D layout col = lane&15, row = (lane>>4)*4 + reg
    const int orow0 = row0 + wm * 64 + fg * 4;
    const int ocol0 = col0 + wn * 64 + fr;
#pragma unroll
    for (int n2 = 0; n2 < 4; ++n2) {
        float bv = bias[ocol0 + n2 * 16];
#pragma unroll
        for (int m2 = 0; m2 < 4; ++m2) {
#pragma unroll
            for (int r = 0; r < 4; ++r) {
                y[(size_t)(orow0 + m2 * 16 + r) * DOUT + (ocol0 + n2 * 16)]
                    = acc[m2][n2][r] + bv;
            }
        }
    }
}

extern "C" void kernel_launch(void* const* d_in, const int* in_sizes, int n_in,
                              void* d_out, int out_size, void* d_ws, size_t ws_size,
                              hipStream_t stream)
{
    const float* x          = (const float*)d_in[0];
    const float* coef       = (const float*)d_in[1];
    const float* scale_base = (const float*)d_in[2];
    const float* scale_sp   = (const float*)d_in[3];
    const float* bias       = (const float*)d_in[4];
    unsigned short* wt = (unsigned short*)d_ws;   // needs 4 MB (2 ntiles * 64 kt * 32 KB)
    float* y = (float*)d_out;

    kan_prep<<<1024, 256, 0, stream>>>(coef, scale_base, scale_sp, wt);
    kan_gemm<<<256, 512, 0, stream>>>(x, wt, bias, y);
}